// Round 4
// baseline (85.369 us; speedup 1.0000x reference)
//
#include <hip/hip_runtime.h>
#include <hip/hip_cooperative_groups.h>

namespace cg = cooperative_groups;

// N=256, A=1024, B=128, C=16
//   act = inp @ theta.reshape(1024, 2048)            [256, 2048] (bf16 MFMA)
//   d[i,j,b] = sum_c |act[j,b,c] - act[i,b,c]|
//   mb[j,b]  = (sum_i exp(-d[i,j,b]) - 1) / 255
//   out = concat([inp, mb], axis=1)                  [256, 1152] fp32
//
// Single cooperative kernel, 256 blocks (1/CU, co-resident), 256 threads.
// Phase 1: bf16-MFMA GEMM with register double-buffered staging.
// grid.sync()
// Phase 2: each block does 2 pairwise units (b, jq).

#define NN 256
#define AA 1024
#define CC 16
#define NBB 2048       // B*C
#define OUTW 1152      // A + B

typedef __attribute__((ext_vector_type(4))) float f32x4;
typedef __attribute__((ext_vector_type(8))) short bf16x8;
typedef __attribute__((ext_vector_type(4))) unsigned int u32x4;

// pack two fp32 -> two bf16 (truncation) in ONE v_perm_b32.
__device__ __forceinline__ unsigned int pack_bf2(float lo, float hi) {
    union { float f; unsigned u; } a, b;
    a.f = lo; b.f = hi;
    return __builtin_amdgcn_perm(b.u, a.u, 0x07060302u);
}

__global__ __launch_bounds__(256) void fused_kernel(const float* __restrict__ inp,
                                                    const float* __restrict__ theta,
                                                    float* __restrict__ act,
                                                    float* __restrict__ out) {
    __shared__ float smem[NN * 20];                       // 20 KiB
    unsigned short* const As = (unsigned short*)smem;     // 4 KiB  [32 m][64 k]
    unsigned short* const Bs = (unsigned short*)(smem + 1024); // 8 KiB [64 n][64 k]
    char* const Asb = (char*)As;
    char* const Bsb = (char*)Bs;

    const int tid = threadIdx.x;
    const int lane = tid & 63;
    const int w = tid >> 6;
    const int wn = w & 1, wm = w >> 1;
    const int bn = blockIdx.x, bm = blockIdx.y;
    const int col0 = bn * 64, row0 = bm * 32;

    // ================= phase 1: GEMM (tile 32x64, BK=64, 16 ktiles) =========
    const int am = tid >> 3;           // A-stage row 0..31
    const int ak8 = (tid & 7) * 8;     // 8 consecutive k
    const int k2r0 = tid >> 4;         // B-stage r=0: k-pair 0..15
    const int n4r0 = tid & 15;
    const int k2r1 = (tid + 256) >> 4; // B-stage r=1: k-pair 16..31
    const int n4r1 = n4r0;

    f32x4 acc[2] = {};
    f32x4 a0, a1, bl0, bh0, bl1, bh1;

    // prologue: load ktile 0 into registers
    {
        const float* asrc = inp + (row0 + am) * AA + ak8;
        a0 = *(const f32x4*)asrc; a1 = *(const f32x4*)(asrc + 4);
        const float* s0 = theta + (k2r0 * 2) * NBB + col0 + n4r0 * 4;
        bl0 = *(const f32x4*)s0; bh0 = *(const f32x4*)(s0 + NBB);
        const float* s1 = theta + (k2r1 * 2) * NBB + col0 + n4r1 * 4;
        bl1 = *(const f32x4*)s1; bh1 = *(const f32x4*)(s1 + NBB);
    }

    for (int kt = 0; kt < 16; ++kt) {
        // convert current tile (in regs) to packed bf16
        u32x4 ha;
        ha.x = pack_bf2(a0.x, a0.y); ha.y = pack_bf2(a0.z, a0.w);
        ha.z = pack_bf2(a1.x, a1.y); ha.w = pack_bf2(a1.z, a1.w);
        unsigned int hb0[4], hb1[4];
        {
            const float* l0 = (const float*)&bl0; const float* h0 = (const float*)&bh0;
            const float* l1 = (const float*)&bl1; const float* h1 = (const float*)&bh1;
            #pragma unroll
            for (int c = 0; c < 4; ++c) {
                hb0[c] = pack_bf2(l0[c], h0[c]);
                hb1[c] = pack_bf2(l1[c], h1[c]);
            }
        }
        __syncthreads();   // previous MFMA reads finished
        *(u32x4*)(Asb + ((am * 128 + ak8 * 2) ^ ((am & 7) << 4))) = ha;
        #pragma unroll
        for (int c = 0; c < 4; ++c) {
            const int n0 = n4r0 * 4 + c;
            *(unsigned int*)(Bsb + ((n0 * 128 + k2r0 * 4) ^ ((n0 & 7) << 4))) = hb0[c];
            const int n1 = n4r1 * 4 + c;
            *(unsigned int*)(Bsb + ((n1 * 128 + k2r1 * 4) ^ ((n1 & 7) << 4))) = hb1[c];
        }
        // prefetch next ktile (overlaps with barrier + MFMA below)
        if (kt < 15) {
            const int k0n = (kt + 1) * 64;
            const float* asrc = inp + (row0 + am) * AA + k0n + ak8;
            a0 = *(const f32x4*)asrc; a1 = *(const f32x4*)(asrc + 4);
            const float* s0 = theta + (k0n + k2r0 * 2) * NBB + col0 + n4r0 * 4;
            bl0 = *(const f32x4*)s0; bh0 = *(const f32x4*)(s0 + NBB);
            const float* s1 = theta + (k0n + k2r1 * 2) * NBB + col0 + n4r1 * 4;
            bl1 = *(const f32x4*)s1; bh1 = *(const f32x4*)(s1 + NBB);
        }
        __syncthreads();   // tile staged
        #pragma unroll
        for (int ks = 0; ks < 2; ++ks) {
            const int kbyte = ks * 64 + (lane >> 4) * 16;
            const int m = wm * 16 + (lane & 15);
            const bf16x8 af = *(bf16x8*)(Asb + ((m * 128 + kbyte) ^ ((m & 7) << 4)));
            #pragma unroll
            for (int nf = 0; nf < 2; ++nf) {
                const int n = wn * 32 + nf * 16 + (lane & 15);
                const bf16x8 bfv = *(bf16x8*)(Bsb + ((n * 128 + kbyte) ^ ((n & 7) << 4)));
                acc[nf] = __builtin_amdgcn_mfma_f32_16x16x32_bf16(af, bfv, acc[nf], 0, 0, 0);
            }
        }
    }
    // epilogue: C/D layout col = lane&15, row = (lane>>4)*4 + r
    #pragma unroll
    for (int nf = 0; nf < 2; ++nf) {
        const int col = col0 + wn * 32 + nf * 16 + (lane & 15);
        #pragma unroll
        for (int r = 0; r < 4; ++r) {
            const int row = row0 + wm * 16 + (lane >> 4) * 4 + r;
            act[row * NBB + col] = acc[nf][r];
        }
    }
    // fused copy: this block's 32x32 patch of inp -> out[:, :1024]
    {
        const int mr = row0 + (tid >> 3);
        const int c = bn * 32 + (tid & 7) * 4;
        *(f32x4*)(out + mr * OUTW + c) = *(const f32x4*)(inp + mr * AA + c);
    }

    __threadfence();
    cg::this_grid().sync();

    // ================= phase 2: pairwise exp(-L1), 2 units/block ============
    const int bid = bm * 32 + bn;        // 0..255
    const int jg = tid >> 4;             // 0..15
    const int q = tid & 15;              // 0..15

    #pragma unroll
    for (int u = 0; u < 2; ++u) {
        const int unit = bid * 2 + u;    // 0..511
        const int b = unit >> 2;         // 0..127
        const int jq = unit & 3;

        if (u) __syncthreads();          // previous unit's reads done
        #pragma unroll
        for (int r = 0; r < 4; ++r) {
            const int v = tid + r * 256;          // 1024 f32x4 tasks
            const int i = v >> 2, c4 = v & 3;
            *(f32x4*)(smem + i * 20 + c4 * 4) =
                *(const f32x4*)(act + i * NBB + b * CC + c4 * 4);
        }
        __syncthreads();

        const int j0 = jq * 64 + jg * 4;
        float ar[4][16];
        #pragma unroll
        for (int jj = 0; jj < 4; ++jj)
            #pragma unroll
            for (int c = 0; c < 16; ++c)
                ar[jj][c] = smem[(j0 + jj) * 20 + c];

        float s[4] = {0.f, 0.f, 0.f, 0.f};
        #pragma unroll 2
        for (int ii = 0; ii < 16; ++ii) {
            const float* row = smem + (ii * 16 + q) * 20;
            float rv[16];
            #pragma unroll
            for (int c4 = 0; c4 < 4; ++c4)
                *(f32x4*)(rv + c4 * 4) = *(const f32x4*)(row + c4 * 4);
            #pragma unroll
            for (int jj = 0; jj < 4; ++jj) {
                float d = 0.f;
                #pragma unroll
                for (int c = 0; c < 16; ++c) d += fabsf(rv[c] - ar[jj][c]);
                s[jj] += __expf(-d);
            }
        }
        #pragma unroll
        for (int jj = 0; jj < 4; ++jj) {
            s[jj] += __shfl_xor(s[jj], 1);
            s[jj] += __shfl_xor(s[jj], 2);
            s[jj] += __shfl_xor(s[jj], 4);
            s[jj] += __shfl_xor(s[jj], 8);
        }
        if (q == 0) {
            #pragma unroll
            for (int jj = 0; jj < 4; ++jj)
                out[(j0 + jj) * OUTW + AA + b] = (s[jj] - 1.0f) * (1.0f / 255.0f);
        }
    }
}

extern "C" void kernel_launch(void* const* d_in, const int* in_sizes, int n_in,
                              void* d_out, int out_size, void* d_ws, size_t ws_size,
                              hipStream_t stream) {
    const float* inp = (const float*)d_in[0];     // [256][1024]
    const float* theta = (const float*)d_in[1];   // [1024][2048]
    float* out = (float*)d_out;                   // [256][1152]
    float* act = (float*)d_ws;                    // 256*2048 f32 = 2 MiB

    void* args[] = {(void*)&inp, (void*)&theta, (void*)&act, (void*)&out};
    hipLaunchCooperativeKernel((const void*)fused_kernel, dim3(32, 8), dim3(256),
                               args, 0, stream);
}

// Round 5
// 22.713 us; speedup vs baseline: 3.7586x; 3.7586x over previous
//
#include <hip/hip_runtime.h>

// N=256, A=1024, B=128, C=16
//   act = inp @ theta.reshape(1024, 2048)            (bf16 MFMA, split-K=2)
//   d[i,j,b] = sum_c |act[j,b,c] - act[i,b,c]|
//   mb[j,b]  = (sum_i exp(-d[i,j,b]) - 1) / 255
//   out = concat([inp, mb], axis=1)                  [256, 1152] fp32

#define NN 256
#define AA 1024
#define CC 16
#define NBB 2048       // B*C
#define OUTW 1152      // A + B
#define PHALF 524288   // one split-K partial: 128*256*16 fp32 elements (2 MiB)

typedef __attribute__((ext_vector_type(4))) float f32x4;
typedef __attribute__((ext_vector_type(8))) short bf16x8;
typedef __attribute__((ext_vector_type(4))) unsigned int u32x4;

// pack two fp32 -> two bf16 (truncation) in ONE v_perm_b32.
__device__ __forceinline__ unsigned int pack_bf2(float lo, float hi) {
    union { float f; unsigned u; } a, b;
    a.f = lo; b.f = hi;
    return __builtin_amdgcn_perm(b.u, a.u, 0x07060302u);
}

// ---------------------------------------------------------------------------
// Kernel 1: bf16-MFMA GEMM, tile 32m x 64n, BK=64, split-K=2 (8 ktiles each).
// Grid (32 bn, 8 bm, 2 ks) = 512 blocks (2/CU, 2 waves/SIMD), 256 threads.
// A: thread loads 8 consecutive k of one m (2 f32x4), packs, one b128 write.
// B: thread loads 16 k's of ONE n (16 coalesced b32), packs, two b128 writes
//    -> write banks (n&7)<<2 spread, 2-way max (free).
// LDS [n][k] / [m][k] bf16, rows 128 B, XOR swizzle byte^=(row&7)<<4.
// Register prefetch of next ktile overlaps the LDS-write window.
// Output partials in transposed layout part[ks][b][i][c] (b = col/16).
// ---------------------------------------------------------------------------
__global__ __launch_bounds__(256) void gemm_kernel(const float* __restrict__ inp,
                                                   const float* __restrict__ theta,
                                                   float* __restrict__ part,
                                                   float* __restrict__ out) {
    const int tid = threadIdx.x;
    const int lane = tid & 63;
    const int w = tid >> 6;
    const int wn = w & 1, wm = w >> 1;
    const int col0 = blockIdx.x * 64;
    const int row0 = blockIdx.y * 32;
    const int ks = blockIdx.z;
    const int kbase = ks * 512;

    __shared__ unsigned short As[32 * 64];  // 4 KiB  [m][k]
    __shared__ unsigned short Bs[64 * 64];  // 8 KiB  [n][k]
    char* const Asb = (char*)As;
    char* const Bsb = (char*)Bs;

    const int am = tid >> 3, ach = tid & 7;   // A stage: row, 16B chunk
    const int nb = tid & 63, kq = tid >> 6;   // B stage: n row, k quarter

    f32x4 a0, a1;
    float bv[16];

    // prologue: ktile 0 into registers
    {
        const float* asrc = inp + (row0 + am) * AA + kbase + ach * 8;
        a0 = *(const f32x4*)asrc; a1 = *(const f32x4*)(asrc + 4);
        const float* bsrc = theta + (kbase + kq * 16) * NBB + col0 + nb;
        #pragma unroll
        for (int u = 0; u < 16; ++u) bv[u] = bsrc[u * NBB];
    }

    f32x4 acc[2] = {};

    for (int kt = 0; kt < 8; ++kt) {
        // convert current tile to packed bf16
        u32x4 ha, hb0, hb1;
        ha.x = pack_bf2(a0.x, a0.y); ha.y = pack_bf2(a0.z, a0.w);
        ha.z = pack_bf2(a1.x, a1.y); ha.w = pack_bf2(a1.z, a1.w);
        hb0.x = pack_bf2(bv[0], bv[1]);   hb0.y = pack_bf2(bv[2], bv[3]);
        hb0.z = pack_bf2(bv[4], bv[5]);   hb0.w = pack_bf2(bv[6], bv[7]);
        hb1.x = pack_bf2(bv[8], bv[9]);   hb1.y = pack_bf2(bv[10], bv[11]);
        hb1.z = pack_bf2(bv[12], bv[13]); hb1.w = pack_bf2(bv[14], bv[15]);

        __syncthreads();   // previous MFMA reads done
        *(u32x4*)(Asb + ((am * 128 + ach * 16) ^ ((am & 7) << 4))) = ha;
        {
            const int bbase = nb * 128 + kq * 32;
            const int swz = (nb & 7) << 4;
            *(u32x4*)(Bsb + (bbase ^ swz)) = hb0;
            *(u32x4*)(Bsb + ((bbase + 16) ^ swz)) = hb1;
        }
        // prefetch next ktile (overlaps LDS writes; drained at next barrier)
        if (kt < 7) {
            const int k0n = kbase + (kt + 1) * 64;
            const float* asrc = inp + (row0 + am) * AA + k0n + ach * 8;
            a0 = *(const f32x4*)asrc; a1 = *(const f32x4*)(asrc + 4);
            const float* bsrc = theta + (k0n + kq * 16) * NBB + col0 + nb;
            #pragma unroll
            for (int u = 0; u < 16; ++u) bv[u] = bsrc[u * NBB];
        }
        __syncthreads();   // tile staged
        #pragma unroll
        for (int ks2 = 0; ks2 < 2; ++ks2) {
            const int kbyte = ks2 * 64 + (lane >> 4) * 16;
            const int m = wm * 16 + (lane & 15);
            const bf16x8 af = *(bf16x8*)(Asb + ((m * 128 + kbyte) ^ ((m & 7) << 4)));
            #pragma unroll
            for (int nf = 0; nf < 2; ++nf) {
                const int n = wn * 32 + nf * 16 + (lane & 15);
                const bf16x8 bfv = *(bf16x8*)(Bsb + ((n * 128 + kbyte) ^ ((n & 7) << 4)));
                acc[nf] = __builtin_amdgcn_mfma_f32_16x16x32_bf16(af, bfv, acc[nf], 0, 0, 0);
            }
        }
    }

    // epilogue: partial in [ks][b][i][c]; C/D layout col=lane&15, row=(lane>>4)*4+r
    float* p = part + (size_t)ks * PHALF;
    #pragma unroll
    for (int nf = 0; nf < 2; ++nf) {
        const int col = col0 + wn * 32 + nf * 16 + (lane & 15);
        const int bcol = col >> 4, c = col & 15;
        #pragma unroll
        for (int r = 0; r < 4; ++r) {
            const int row = row0 + wm * 16 + (lane >> 4) * 4 + r;
            p[bcol * (NN * CC) + row * CC + c] = acc[nf][r];
        }
    }
    // fused copy (once): this block's 32x32 patch of inp -> out[:, :1024]
    if (ks == 0) {
        const int mr = row0 + (tid >> 3);
        const int c = blockIdx.x * 32 + (tid & 7) * 4;
        *(f32x4*)(out + mr * OUTW + c) = *(const f32x4*)(inp + mr * AA + c);
    }
}

// ---------------------------------------------------------------------------
// Kernel 2: pairwise exp(-L1), j-register-blocked (Jt=4), split-K sum in
// staging. Grid (128 b, 4 jq) = 512 blocks, 256 threads. Unit's column block
// is CONTIGUOUS 16 KiB per partial -> perfectly coalesced staging.
// LDS rows padded to 20 floats (2-way alias max).
// ---------------------------------------------------------------------------
__global__ __launch_bounds__(256) void pair_kernel(const float* __restrict__ part,
                                                   float* __restrict__ out) {
    const int b = blockIdx.x;       // 0..127
    const int jq = blockIdx.y;      // 0..3
    const int tid = threadIdx.x;

    __shared__ float sA[NN * 20];   // 20 KiB

    const float* p0 = part + (size_t)b * (NN * CC);
    const float* p1 = p0 + PHALF;

    #pragma unroll
    for (int r = 0; r < 4; ++r) {
        const int v = tid + r * 256;          // 1024 f32x4 tasks
        const int i = v >> 2, c4 = v & 3;
        const f32x4 x0 = *(const f32x4*)(p0 + v * 4);
        const f32x4 x1 = *(const f32x4*)(p1 + v * 4);
        f32x4 s; s.x = x0.x + x1.x; s.y = x0.y + x1.y;
        s.z = x0.z + x1.z; s.w = x0.w + x1.w;
        *(f32x4*)(sA + i * 20 + c4 * 4) = s;
    }
    __syncthreads();

    const int jg = tid >> 4;        // 0..15
    const int q = tid & 15;         // 0..15
    const int j0 = jq * 64 + jg * 4;

    float ar[4][16];
    #pragma unroll
    for (int jj = 0; jj < 4; ++jj)
        #pragma unroll
        for (int c = 0; c < 16; ++c)
            ar[jj][c] = sA[(j0 + jj) * 20 + c];

    float s[4] = {0.f, 0.f, 0.f, 0.f};
    #pragma unroll 2
    for (int ii = 0; ii < 16; ++ii) {
        const float* row = sA + (ii * 16 + q) * 20;
        float rv[16];
        #pragma unroll
        for (int c4 = 0; c4 < 4; ++c4)
            *(f32x4*)(rv + c4 * 4) = *(const f32x4*)(row + c4 * 4);
        #pragma unroll
        for (int jj = 0; jj < 4; ++jj) {
            float d = 0.f;
            #pragma unroll
            for (int c = 0; c < 16; ++c) d += fabsf(rv[c] - ar[jj][c]);
            s[jj] += __expf(-d);
        }
    }
    #pragma unroll
    for (int jj = 0; jj < 4; ++jj) {
        s[jj] += __shfl_xor(s[jj], 1);
        s[jj] += __shfl_xor(s[jj], 2);
        s[jj] += __shfl_xor(s[jj], 4);
        s[jj] += __shfl_xor(s[jj], 8);
    }
    if (q == 0) {
        #pragma unroll
        for (int jj = 0; jj < 4; ++jj)
            out[(j0 + jj) * OUTW + AA + b] = (s[jj] - 1.0f) * (1.0f / 255.0f);
    }
}

extern "C" void kernel_launch(void* const* d_in, const int* in_sizes, int n_in,
                              void* d_out, int out_size, void* d_ws, size_t ws_size,
                              hipStream_t stream) {
    const float* inp = (const float*)d_in[0];     // [256][1024]
    const float* theta = (const float*)d_in[1];   // [1024][2048]
    float* out = (float*)d_out;                   // [256][1152]
    float* part = (float*)d_ws;                   // 2 partials, 4 MiB total

    gemm_kernel<<<dim3(32, 8, 2), 256, 0, stream>>>(inp, theta, part, out);
    pair_kernel<<<dim3(128, 4), 256, 0, stream>>>(part, out);
}

// Round 6
// 21.749 us; speedup vs baseline: 3.9252x; 1.0443x over previous
//
#include <hip/hip_runtime.h>

// N=256, A=1024, B=128, C=16
//   act = inp @ theta.reshape(1024, 2048)            (bf16 MFMA, split-K=2)
//   d[i,j,b] = sum_c |act[j,b,c] - act[i,b,c]|
//   mb[j,b]  = (sum_i exp(-d[i,j,b]) - 1) / 255
//   out = concat([inp, mb], axis=1)                  [256, 1152] fp32

#define NN 256
#define AA 1024
#define CC 16
#define NBB 2048       // B*C
#define OUTW 1152      // A + B
#define PHALF_E (128 * 256 * 16)   // elements per split-K partial (bf16, 1 MiB)

typedef __attribute__((ext_vector_type(4))) float f32x4;
typedef __attribute__((ext_vector_type(8))) short bf16x8;
typedef __attribute__((ext_vector_type(4))) unsigned int u32x4;
typedef __attribute__((ext_vector_type(8))) unsigned short u16x8;

// pack two fp32 -> two bf16 (truncation) in ONE v_perm_b32.
__device__ __forceinline__ unsigned int pack_bf2(float lo, float hi) {
    union { float f; unsigned u; } a, b;
    a.f = lo; b.f = hi;
    return __builtin_amdgcn_perm(b.u, a.u, 0x07060302u);
}

__device__ __forceinline__ unsigned short f2bf_trunc(float x) {
    union { float f; unsigned u; } v; v.f = x;
    return (unsigned short)(v.u >> 16);
}

__device__ __forceinline__ float bf2f(unsigned short h) {
    union { unsigned u; float f; } v; v.u = ((unsigned)h) << 16;
    return v.f;
}

// barrier that does NOT drain vmcnt: LDS visibility only. Prefetch global
// loads stay in flight across it (T4: counted-vmcnt analog; the compiler's
// own register-dependency vmcnt waits handle correctness of the consumers).
__device__ __forceinline__ void barrier_keep_loads() {
    asm volatile("s_waitcnt lgkmcnt(0)" ::: "memory");
    __builtin_amdgcn_s_barrier();
    __builtin_amdgcn_sched_barrier(0);
}

// ---------------------------------------------------------------------------
// Kernel 1: bf16-MFMA GEMM, tile 32m x 64n, BK=64, split-K=2 (8 ktiles).
// Grid (32 bn, 8 bm, 2 ks) = 512 blocks (2/CU), 256 threads (4 waves, 2x2).
// Double-buffered LDS (24 KiB), ONE raw barrier per ktile, depth-2 register
// prefetch pipeline: iter kt loads T_{kt+2}, computes T_kt, packs T_{kt+1}.
// LDS [m][k]/[n][k] bf16 rows 128 B, XOR swizzle byte ^= (row&7)<<4.
// Output: bf16 partials part[ks][b][i][c] (b = col/16). ks==0 blocks also
// copy their 32x32 inp patch to out[:, :1024].
// ---------------------------------------------------------------------------
__global__ __launch_bounds__(256) void gemm_kernel(const float* __restrict__ inp,
                                                   const float* __restrict__ theta,
                                                   unsigned short* __restrict__ part,
                                                   float* __restrict__ out) {
    const int tid = threadIdx.x;
    const int lane = tid & 63;
    const int w = tid >> 6;
    const int wn = w & 1, wm = w >> 1;
    const int col0 = blockIdx.x * 64;
    const int row0 = blockIdx.y * 32;
    const int ks = blockIdx.z;
    const int kbase = ks * 512;

    __shared__ unsigned short As[2][32 * 64];   // 2 x 4 KiB  [m][k]
    __shared__ unsigned short Bs[2][64 * 64];   // 2 x 8 KiB  [n][k]

    const int am = tid >> 3, ach = tid & 7;     // A stage: row, 16B chunk
    const int nb = tid & 63, kq = tid >> 6;     // B stage: n row, k quarter

    const float* const abase = inp + (row0 + am) * AA + kbase + ach * 8;
    const float* const bbase = theta + (kbase + kq * 16) * NBB + col0 + nb;

    f32x4 a0[2], a1[2];
    float bv[2][16];

    // prologue: T0 -> set0, T1 -> set1; pack T0 -> buf0
    #pragma unroll
    for (int s = 0; s < 2; ++s) {
        const float* asrc = abase + s * 64;
        a0[s] = *(const f32x4*)asrc; a1[s] = *(const f32x4*)(asrc + 4);
        const float* bsrc = bbase + s * 64 * NBB;
        #pragma unroll
        for (int u = 0; u < 16; ++u) bv[s][u] = bsrc[u * NBB];
    }

    f32x4 acc[2] = {};

    #pragma unroll
    for (int kt = 0; kt < 8; ++kt) {
        // ---- pack T_kt's predecessor / stage current: on kt==0 pack T0 ----
        if (kt == 0) {
            char* Asb = (char*)As[0];
            char* Bsb = (char*)Bs[0];
            u32x4 ha;
            ha.x = pack_bf2(a0[0].x, a0[0].y); ha.y = pack_bf2(a0[0].z, a0[0].w);
            ha.z = pack_bf2(a1[0].x, a1[0].y); ha.w = pack_bf2(a1[0].z, a1[0].w);
            *(u32x4*)(Asb + ((am * 128 + ach * 16) ^ ((am & 7) << 4))) = ha;
            u32x4 hb0, hb1;
            hb0.x = pack_bf2(bv[0][0], bv[0][1]);   hb0.y = pack_bf2(bv[0][2], bv[0][3]);
            hb0.z = pack_bf2(bv[0][4], bv[0][5]);   hb0.w = pack_bf2(bv[0][6], bv[0][7]);
            hb1.x = pack_bf2(bv[0][8], bv[0][9]);   hb1.y = pack_bf2(bv[0][10], bv[0][11]);
            hb1.z = pack_bf2(bv[0][12], bv[0][13]); hb1.w = pack_bf2(bv[0][14], bv[0][15]);
            const int bb = nb * 128 + kq * 32, swz = (nb & 7) << 4;
            *(u32x4*)(Bsb + (bb ^ swz)) = hb0;
            *(u32x4*)(Bsb + ((bb + 16) ^ swz)) = hb1;
            barrier_keep_loads();
        }
        // ---- issue loads for T_{kt+2} into set[kt&1] (frees T_kt's set) ----
        if (kt < 6) {
            const int s = kt & 1;
            const float* asrc = abase + (kt + 2) * 64;
            a0[s] = *(const f32x4*)asrc; a1[s] = *(const f32x4*)(asrc + 4);
            const float* bsrc = bbase + (size_t)(kt + 2) * 64 * NBB;
            #pragma unroll
            for (int u = 0; u < 16; ++u) bv[s][u] = bsrc[u * NBB];
        }
        // ---- MFMA from buf[kt&1] ----
        {
            char* Asb = (char*)As[kt & 1];
            char* Bsb = (char*)Bs[kt & 1];
            #pragma unroll
            for (int ks2 = 0; ks2 < 2; ++ks2) {
                const int kbyte = ks2 * 64 + (lane >> 4) * 16;
                const int m = wm * 16 + (lane & 15);
                const bf16x8 af = *(bf16x8*)(Asb + ((m * 128 + kbyte) ^ ((m & 7) << 4)));
                #pragma unroll
                for (int nf = 0; nf < 2; ++nf) {
                    const int n = wn * 32 + nf * 16 + (lane & 15);
                    const bf16x8 bfv = *(bf16x8*)(Bsb + ((n * 128 + kbyte) ^ ((n & 7) << 4)));
                    acc[nf] = __builtin_amdgcn_mfma_f32_16x16x32_bf16(af, bfv, acc[nf], 0, 0, 0);
                }
            }
        }
        // ---- pack T_{kt+1} from set[(kt+1)&1] into buf[(kt+1)&1] ----
        if (kt < 7) {
            const int s = (kt + 1) & 1;
            char* Asb = (char*)As[s];
            char* Bsb = (char*)Bs[s];
            u32x4 ha;
            ha.x = pack_bf2(a0[s].x, a0[s].y); ha.y = pack_bf2(a0[s].z, a0[s].w);
            ha.z = pack_bf2(a1[s].x, a1[s].y); ha.w = pack_bf2(a1[s].z, a1[s].w);
            *(u32x4*)(Asb + ((am * 128 + ach * 16) ^ ((am & 7) << 4))) = ha;
            u32x4 hb0, hb1;
            hb0.x = pack_bf2(bv[s][0], bv[s][1]);   hb0.y = pack_bf2(bv[s][2], bv[s][3]);
            hb0.z = pack_bf2(bv[s][4], bv[s][5]);   hb0.w = pack_bf2(bv[s][6], bv[s][7]);
            hb1.x = pack_bf2(bv[s][8], bv[s][9]);   hb1.y = pack_bf2(bv[s][10], bv[s][11]);
            hb1.z = pack_bf2(bv[s][12], bv[s][13]); hb1.w = pack_bf2(bv[s][14], bv[s][15]);
            const int bb = nb * 128 + kq * 32, swz = (nb & 7) << 4;
            *(u32x4*)(Bsb + (bb ^ swz)) = hb0;
            *(u32x4*)(Bsb + ((bb + 16) ^ swz)) = hb1;
            barrier_keep_loads();
        }
    }

    // epilogue: bf16 partial [ks][b][i][c]; C/D: col=lane&15, row=(lane>>4)*4+r
    unsigned short* p = part + (size_t)ks * PHALF_E;
    #pragma unroll
    for (int nf = 0; nf < 2; ++nf) {
        const int col = col0 + wn * 32 + nf * 16 + (lane & 15);
        const int bcol = col >> 4, c = col & 15;
        #pragma unroll
        for (int r = 0; r < 4; ++r) {
            const int row = row0 + wm * 16 + (lane >> 4) * 4 + r;
            p[bcol * (NN * CC) + row * CC + c] = f2bf_trunc(acc[nf][r]);
        }
    }
    // fused copy (ks==0 only): 32x32 patch of inp -> out[:, :1024]
    if (ks == 0) {
        const int mr = row0 + (tid >> 3);
        const int c = blockIdx.x * 32 + (tid & 7) * 4;
        *(f32x4*)(out + mr * OUTW + c) = *(const f32x4*)(inp + mr * AA + c);
    }
}

// ---------------------------------------------------------------------------
// Kernel 2: pairwise exp(-L1), Jt=4, bf16 split-K partial sum in staging.
// Grid (128 b, 4 jq) = 512 blocks, 256 threads. Each thread stages one row
// (16 bf16 from each partial = 2x16B coalesced), converts+sums to fp32 LDS
// rows padded to 20 floats. Inner loop: 4 j's in registers, i = ii*16 + q.
// ---------------------------------------------------------------------------
__global__ __launch_bounds__(256) void pair_kernel(const unsigned short* __restrict__ part,
                                                   float* __restrict__ out) {
    const int b = blockIdx.x;       // 0..127
    const int jq = blockIdx.y;      // 0..3
    const int tid = threadIdx.x;

    __shared__ float sA[NN * 20];   // 20 KiB

    const unsigned short* p0 = part + (size_t)b * (NN * CC);
    const unsigned short* p1 = p0 + PHALF_E;

    {   // thread tid stages row i = tid
        const u16x8 x0a = *(const u16x8*)(p0 + tid * CC);
        const u16x8 x0b = *(const u16x8*)(p0 + tid * CC + 8);
        const u16x8 x1a = *(const u16x8*)(p1 + tid * CC);
        const u16x8 x1b = *(const u16x8*)(p1 + tid * CC + 8);
        float* dst = sA + tid * 20;
        #pragma unroll
        for (int e = 0; e < 8; ++e) dst[e] = bf2f(x0a[e]) + bf2f(x1a[e]);
        #pragma unroll
        for (int e = 0; e < 8; ++e) dst[8 + e] = bf2f(x0b[e]) + bf2f(x1b[e]);
    }
    __syncthreads();

    const int jg = tid >> 4;        // 0..15
    const int q = tid & 15;         // 0..15
    const int j0 = jq * 64 + jg * 4;

    float ar[4][16];
    #pragma unroll
    for (int jj = 0; jj < 4; ++jj)
        #pragma unroll
        for (int c = 0; c < 16; ++c)
            ar[jj][c] = sA[(j0 + jj) * 20 + c];

    float s[4] = {0.f, 0.f, 0.f, 0.f};
    #pragma unroll 4
    for (int ii = 0; ii < 16; ++ii) {
        const float* row = sA + (ii * 16 + q) * 20;
        float rv[16];
        #pragma unroll
        for (int c4 = 0; c4 < 4; ++c4)
            *(f32x4*)(rv + c4 * 4) = *(const f32x4*)(row + c4 * 4);
        #pragma unroll
        for (int jj = 0; jj < 4; ++jj) {
            float d = 0.f;
            #pragma unroll
            for (int c = 0; c < 16; ++c) d += fabsf(rv[c] - ar[jj][c]);
            s[jj] += __expf(-d);
        }
    }
    #pragma unroll
    for (int jj = 0; jj < 4; ++jj) {
        s[jj] += __shfl_xor(s[jj], 1);
        s[jj] += __shfl_xor(s[jj], 2);
        s[jj] += __shfl_xor(s[jj], 4);
        s[jj] += __shfl_xor(s[jj], 8);
    }
    if (q == 0) {
        #pragma unroll
        for (int jj = 0; jj < 4; ++jj)
            out[(j0 + jj) * OUTW + AA + b] = (s[jj] - 1.0f) * (1.0f / 255.0f);
    }
}

extern "C" void kernel_launch(void* const* d_in, const int* in_sizes, int n_in,
                              void* d_out, int out_size, void* d_ws, size_t ws_size,
                              hipStream_t stream) {
    const float* inp = (const float*)d_in[0];     // [256][1024]
    const float* theta = (const float*)d_in[1];   // [1024][2048]
    float* out = (float*)d_out;                   // [256][1152]
    unsigned short* part = (unsigned short*)d_ws; // 2 bf16 partials, 2 MiB

    gemm_kernel<<<dim3(32, 8, 2), 256, 0, stream>>>(inp, theta, part, out);
    pair_kernel<<<dim3(128, 4), 256, 0, stream>>>(part, out);
}